// Round 10
// baseline (4241.327 us; speedup 1.0000x reference)
//
#include <hip/hip_runtime.h>
#include <cstdint>
#include <cstddef>

namespace {

constexpr int H    = 300;
constexpr int G4   = 1200;   // 4*H
constexpr int B    = 128;
constexpr int T    = 512;
constexpr int NVOC = 2514;

typedef __attribute__((ext_vector_type(8))) short  short8;
typedef __attribute__((ext_vector_type(4))) float  f32x4;

__device__ __forceinline__ float sigm(float x)     { return 1.f / (1.f + __expf(-x)); }
__device__ __forceinline__ float tanhfast(float x) { return 1.f - 2.f / (__expf(2.f*x) + 1.f); }

__device__ __forceinline__ unsigned short bf16_rn(float f) {
    unsigned u = __float_as_uint(f);
    u += 0x7FFFu + ((u >> 16) & 1u);
    return (unsigned short)(u >> 16);
}
__device__ __forceinline__ float bf16_f(unsigned short s) {
    return __uint_as_float(((unsigned)s) << 16);
}
__device__ __forceinline__ unsigned pack2(unsigned short lo16, unsigned short hi16) {
    return (unsigned)lo16 | ((unsigned)hi16 << 16);
}

// packed h layout: idx(t, hgseg, b, u) = ((t*15 + hgseg)*128 + b)*20 + u
// t-slice = 153600 B, 128B-aligned-disjoint -> first-touch freshness per t.
constexpr int TSEG = 15 * 128 * 20;   // floats per t-slice (38400)

// ---------------------------------------------------------------------------
// MFMA split-precision GEMM. AMODE 0: row=m. 1: embedding gather.
// 2: [b,t]<->[t,b] permute. 3: A is packed-h (row m -> b=m>>9, t=m&511,
// col translated per-segment).
// ---------------------------------------------------------------------------
template<int AMODE, bool HASB2>
__global__ __launch_bounds__(256)
void gemm_mfma(const float* __restrict__ A, const float* __restrict__ W,
               const float* __restrict__ b1, const float* __restrict__ b2,
               const int* __restrict__ tok, float* __restrict__ out, int N)
{
    __shared__ __align__(16) unsigned short Ah[128][40], Al[128][40];
    __shared__ __align__(16) unsigned short Wh[128][40], Wl[128][40];

    const int tid = threadIdx.x;
    const int m0 = blockIdx.y * 128, n0 = blockIdx.x * 128;
    const int rl = tid >> 1, cb = (tid & 1) * 16;

    const int m = m0 + rl;
    const float* aptr;
    if (AMODE == 0) aptr = A + (size_t)m * H;
    else if (AMODE == 3) aptr = A + (size_t)(m & 511) * TSEG + (m >> 9) * 20;
    else {
        const int q = ((m & 127) << 9) + (m >> 7);
        aptr = A + (size_t)((AMODE == 1) ? tok[q] : q) * H;
    }
    const int nrow = n0 + rl;
    const float* wptr = W + (size_t)nrow * H;
    const bool nok = (nrow < N);

    const int wv = tid >> 6, lane = tid & 63;
    const int mw = (wv >> 1) * 64, nw = (wv & 1) * 64;
    const int kg = lane >> 4, mm = lane & 15;

    f32x4 acc[4][4];
#pragma unroll
    for (int i = 0; i < 4; ++i)
#pragma unroll
        for (int j = 0; j < 4; ++j) acc[i][j] = (f32x4){0.f, 0.f, 0.f, 0.f};

    for (int kt = 0; kt < 10; ++kt) {
        const int kbase = kt * 32;
        float4 av[4], wvv[4];
#pragma unroll
        for (int j = 0; j < 4; ++j) {
            const int col = kbase + cb + j * 4;
            const bool kv = (col <= H - 4);
            if (AMODE == 3)
                av[j] = kv ? *(const float4*)(aptr + (col / 20) * 2560 + col % 20)
                           : make_float4(0, 0, 0, 0);
            else
                av[j] = kv ? *(const float4*)(aptr + col) : make_float4(0, 0, 0, 0);
            wvv[j] = (kv && nok) ? *(const float4*)(wptr + col) : make_float4(0, 0, 0, 0);
        }
        __syncthreads();
#pragma unroll
        for (int j = 0; j < 4; ++j) {
            const float a[4] = {av[j].x,  av[j].y,  av[j].z,  av[j].w};
            const float w[4] = {wvv[j].x, wvv[j].y, wvv[j].z, wvv[j].w};
            unsigned short ah[4], al_[4], wh[4], wl[4];
#pragma unroll
            for (int e = 0; e < 4; ++e) {
                ah[e] = bf16_rn(a[e]); al_[e] = bf16_rn(a[e] - bf16_f(ah[e]));
                wh[e] = bf16_rn(w[e]); wl[e]  = bf16_rn(w[e] - bf16_f(wh[e]));
            }
            const int cc = cb + j * 4;
            *(uint2*)&Ah[rl][cc] = make_uint2(pack2(ah[0],ah[1]),  pack2(ah[2],ah[3]));
            *(uint2*)&Al[rl][cc] = make_uint2(pack2(al_[0],al_[1]),pack2(al_[2],al_[3]));
            *(uint2*)&Wh[rl][cc] = make_uint2(pack2(wh[0],wh[1]),  pack2(wh[2],wh[3]));
            *(uint2*)&Wl[rl][cc] = make_uint2(pack2(wl[0],wl[1]),  pack2(wl[2],wl[3]));
        }
        __syncthreads();

        short8 fah[4], fal[4], fbh[4], fbl[4];
#pragma unroll
        for (int f = 0; f < 4; ++f) {
            fah[f] = *(const short8*)&Ah[mw + f*16 + mm][kg*8];
            fal[f] = *(const short8*)&Al[mw + f*16 + mm][kg*8];
            fbh[f] = *(const short8*)&Wh[nw + f*16 + mm][kg*8];
            fbl[f] = *(const short8*)&Wl[nw + f*16 + mm][kg*8];
        }
#pragma unroll
        for (int mf = 0; mf < 4; ++mf)
#pragma unroll
            for (int nf = 0; nf < 4; ++nf) {
                acc[mf][nf] = __builtin_amdgcn_mfma_f32_16x16x32_bf16(fah[mf], fbh[nf], acc[mf][nf], 0, 0, 0);
                acc[mf][nf] = __builtin_amdgcn_mfma_f32_16x16x32_bf16(fal[mf], fbh[nf], acc[mf][nf], 0, 0, 0);
                acc[mf][nf] = __builtin_amdgcn_mfma_f32_16x16x32_bf16(fah[mf], fbl[nf], acc[mf][nf], 0, 0, 0);
            }
    }

    float bias[4];
#pragma unroll
    for (int nf = 0; nf < 4; ++nf) {
        const int n = n0 + nw + nf*16 + mm;
        float v = 0.f;
        if (n < N) { v = b1[n]; if (HASB2) v += b2[n]; }
        bias[nf] = v;
    }
    const int qr = lane >> 4;
#pragma unroll
    for (int mf = 0; mf < 4; ++mf) {
        const int row = m0 + mw + mf*16 + qr*4;
        float* orow = out + (size_t)row * N;
#pragma unroll
        for (int nf = 0; nf < 4; ++nf) {
            const int n = n0 + nw + nf*16 + mm;
            if (n < N) {
#pragma unroll
                for (int r = 0; r < 4; ++r)
                    orow[(size_t)r * N + n] = acc[mf][nf][r] + bias[nf];
            }
        }
    }
}

// ---------------------------------------------------------------------------
// v10 fused recurrence — per-wave flags + plain bulk loads.
// Producer wave: agent-atomic h stores -> s_waitcnt vmcnt(0) -> lane0 relaxed
//   flag store (hand-rolled release; flag value = it+1, monotonic, memset 0
//   per call). Consumer wave: spin on its flag subset (1 load/lane, 45 or 75
//   flags per bg in a few hot lines), compiler-fence, then plain float4 bulk
//   load of its k-quarter (first-touch per t-slice -> fresh, no HW fence),
//   cvt to bf16 hi/lo, stage A-fragments, one barrier.
// vs v9: ~2560 8B atomic transactions/CU/scan -> ~120 flag loads + 304
// coalesced uint4 once. No sentinel fill needed.
// ---------------------------------------------------------------------------
constexpr int HGC = 15;
constexpr int BGC = 16;
constexpr int NWG = HGC * BGC;   // 240
constexpr int A2OFF = 20480;
constexpr int APARF = 40960;
constexpr int GDOFF = 2 * APARF;
constexpr int FLDS  = GDOFF + 10 * 8 * 16 * 4;   // 87040 B

struct Slot { size_t src; int aoff; bool ok; };

__device__ __forceinline__ void slot_init(Slot* sl, int lane, int q, int bg,
                                          int regionOff)
{
#pragma unroll
    for (int j = 0; j < 3; ++j) {
        const int s  = lane + 64 * j;
        const int i4 = s % 19, b = (s / 19) & 7;
        const int k  = q * 76 + i4 * 4;
        sl[j].ok  = (s < 152) && (k < 300);
        sl[j].src = ((size_t)(k / 20) * 128 + bg * 8 + b) * 20 + (k % 20);
        const int kt = k >> 5, kq = (k >> 3) & 3, pos = k & 7;
        sl[j].aoff = regionOff + ((kt * 2) * 4 + kq) * 256 + b * 16 + pos * 2;
    }
}

__device__ __forceinline__ void stage_slots(const Slot* sl,
                                            const float* __restrict__ srcT,
                                            unsigned char* Ap)
{
#pragma unroll
    for (int j = 0; j < 3; ++j)
        if (sl[j].ok) {
            const float4 v = *(const float4*)(srcT + sl[j].src);
            const unsigned short h0 = bf16_rn(v.x), h1_ = bf16_rn(v.y);
            const unsigned short h2_ = bf16_rn(v.z), h3_ = bf16_rn(v.w);
            *(uint2*)(Ap + sl[j].aoff) =
                make_uint2(pack2(h0, h1_), pack2(h2_, h3_));
            *(uint2*)(Ap + sl[j].aoff + 1024) = make_uint2(
                pack2(bf16_rn(v.x - bf16_f(h0)),  bf16_rn(v.y - bf16_f(h1_))),
                pack2(bf16_rn(v.z - bf16_f(h2_)), bf16_rn(v.w - bf16_f(h3_))));
        }
}

__device__ __forceinline__ void wait_flags(const int* __restrict__ f, int cnt,
                                           int lane, int target)
{
    const bool a0 = lane < cnt, a1 = lane + 64 < cnt;
    const int* p0 = f + lane;
    const int* p1 = f + lane + 64;
    for (;;) {
        int v = 0x7fffffff;
        if (a0) v = __hip_atomic_load(p0, __ATOMIC_RELAXED, __HIP_MEMORY_SCOPE_AGENT);
        if (a1) {
            const int w = __hip_atomic_load(p1, __ATOMIC_RELAXED, __HIP_MEMORY_SCOPE_AGENT);
            v = v < w ? v : w;
        }
        if (__all(v >= target)) break;
    }
    asm volatile("" ::: "memory");   // pin bulk loads below the spin
}

// ---- L0 waves (wv 0-2): stage h1 quarter q=NT0/2, MFMA, L0 update ----------
template<int NTN>
__device__ void fused_g0(int lane, int hg, int bg, int NT0,
                         const float* __restrict__ xg0,
                         const float* __restrict__ Whh0,
                         float* __restrict__ h1p, int* __restrict__ f1,
                         unsigned char* __restrict__ Abuf, float (*gd)[8][16])
{
    const int kg = lane >> 4, mm = lane & 15;
    const int q = (NTN == 2) ? (NT0 >> 1) : 2;

    short8 bh[10][NTN], bl[10][NTN];
#pragma unroll
    for (int kt = 0; kt < 10; ++kt)
#pragma unroll
        for (int j = 0; j < NTN; ++j) {
            const int c = (NT0 + j) * 16 + mm;
            const int grow = (c & 3) * H + hg * 20 + (c >> 2);
            short8 hi, lo;
#pragma unroll
            for (int e = 0; e < 8; ++e) {
                const int k = kt * 32 + kg * 8 + e;
                const float v = (k < H) ? Whh0[(size_t)grow * H + k] : 0.f;
                const unsigned short h16 = bf16_rn(v);
                hi[e] = (short)h16;
                lo[e] = (short)bf16_rn(v - bf16_f(h16));
            }
            bh[kt][j] = hi; bl[kt][j] = lo;
        }

    Slot sl[3]; slot_init(sl, lane, q, bg, 0);

    const int sh = (NTN == 2) ? 3 : 2;
    const bool upd = lane < (NTN << 5);
    const int b_u = lane >> sh, u4 = lane & ((1 << sh) - 1);
    const int u_loc = NT0 * 4 + u4;
    const int ntl = NT0 + (u4 >> 2), u_rel = u4 & 3;
    float cst = 0.f;

    const float* xb0 = xg0 + (size_t)(bg * 8 + b_u) * G4 + hg * 20 + u_loc;
    // publish: h1p[((it*15+hg)*128 + bg*8+b_u)*20 + u_loc]
    float* hst = h1p + ((size_t)hg * 128 + bg * 8 + b_u) * 20 + u_loc;
    int* fpub = f1 + hg * 3 + q;

    for (int it = 0; it <= T; ++it) {
        float xv0 = 0.f, xv1 = 0.f, xv2 = 0.f, xv3 = 0.f;
        if (upd && it < T) {
            const float* xb = xb0 + (size_t)it * B * G4;
            xv0 = xb[0]; xv1 = xb[H]; xv2 = xb[2 * H]; xv3 = xb[3 * H];
        }
        unsigned char* Ap = Abuf + (it & 1) * APARF;
        if (it >= 1) {
            wait_flags(f1, 45, lane, it);
            stage_slots(sl, h1p + (size_t)(it - 1) * TSEG, Ap);
        }
        __syncthreads();

        if (it < T) {
            f32x4 a0 = (f32x4){0.f,0.f,0.f,0.f}, a1 = (f32x4){0.f,0.f,0.f,0.f};
#pragma unroll
            for (int kt = 0; kt < 10; ++kt) {
                const short8 ah = *(const short8*)(Ap + ((kt*2+0)*4 + kg)*256 + mm*16);
                const short8 al = *(const short8*)(Ap + ((kt*2+1)*4 + kg)*256 + mm*16);
                a0 = __builtin_amdgcn_mfma_f32_16x16x32_bf16(ah, bh[kt][0], a0, 0, 0, 0);
                a0 = __builtin_amdgcn_mfma_f32_16x16x32_bf16(al, bh[kt][0], a0, 0, 0, 0);
                a0 = __builtin_amdgcn_mfma_f32_16x16x32_bf16(ah, bl[kt][0], a0, 0, 0, 0);
                if (NTN > 1) {
                    a1 = __builtin_amdgcn_mfma_f32_16x16x32_bf16(ah, bh[kt][1], a1, 0, 0, 0);
                    a1 = __builtin_amdgcn_mfma_f32_16x16x32_bf16(al, bh[kt][1], a1, 0, 0, 0);
                    a1 = __builtin_amdgcn_mfma_f32_16x16x32_bf16(ah, bl[kt][1], a1, 0, 0, 0);
                }
            }
            if (lane < 32) {
                const int br = (lane >> 4) * 4;
#pragma unroll
                for (int r = 0; r < 4; ++r) gd[NT0][br + r][mm] = a0[r];
                if (NTN > 1)
#pragma unroll
                    for (int r = 0; r < 4; ++r) gd[NT0 + 1][br + r][mm] = a1[r];
            }
            if (upd) {
                const float* g4 = &gd[ntl][b_u][u_rel * 4];
                const float gi = xv0 + g4[0], gf = xv1 + g4[1];
                const float gz = xv2 + g4[2], go = xv3 + g4[3];
                const float iG = sigm(gi), fG = sigm(gf);
                const float zG = tanhfast(gz), oG = sigm(go);
                cst = fmaf(fG, cst, iG * zG);
                const float hv = oG * tanhfast(cst);
                __hip_atomic_store(hst + (size_t)it * TSEG, hv,
                                   __ATOMIC_RELAXED, __HIP_MEMORY_SCOPE_AGENT);
            }
            asm volatile("s_waitcnt vmcnt(0)" ::: "memory");
            if (lane == 0)
                __hip_atomic_store(fpub, it + 1, __ATOMIC_RELAXED,
                                   __HIP_MEMORY_SCOPE_AGENT);
        }
    }
}

// ---- L1 waves (wv 3-7): stage (h1 q3 | h2 q0-3), dual MFMA, L1 update ------
__device__ void fused_g1(int lane, int hg, int bg, int ntg,
                         const float* __restrict__ stage_src, int stage_delta,
                         int stage_region, int q,
                         const int* __restrict__ wait_f, int wait_cnt,
                         const float* __restrict__ Wih1,
                         const float* __restrict__ Whh1,
                         const float* __restrict__ bih1,
                         const float* __restrict__ bhh1,
                         float* __restrict__ h2p, int* __restrict__ fpub,
                         unsigned char* __restrict__ Abuf, float (*gd)[8][16])
{
    const int kg = lane >> 4, mm = lane & 15;
    const int c = ntg * 16 + mm;
    const int grow = (c & 3) * H + hg * 20 + (c >> 2);

    short8 bIh[10], bIl[10], bHh[10], bHl[10];
#pragma unroll
    for (int kt = 0; kt < 10; ++kt) {
        short8 ih, il, hh, hl;
#pragma unroll
        for (int e = 0; e < 8; ++e) {
            const int k = kt * 32 + kg * 8 + e;
            const float vi = (k < H) ? Wih1[(size_t)grow * H + k] : 0.f;
            const float vh = (k < H) ? Whh1[(size_t)grow * H + k] : 0.f;
            const unsigned short i16 = bf16_rn(vi), h16 = bf16_rn(vh);
            ih[e] = (short)i16; il[e] = (short)bf16_rn(vi - bf16_f(i16));
            hh[e] = (short)h16; hl[e] = (short)bf16_rn(vh - bf16_f(h16));
        }
        bIh[kt] = ih; bIl[kt] = il; bHh[kt] = hh; bHl[kt] = hl;
    }

    Slot sl[3]; slot_init(sl, lane, q, bg, stage_region);

    const bool upd = lane < 32;
    const int b_u = lane >> 2, u4 = lane & 3;
    const int u_loc = ntg * 4 + u4;
    float bias[4];
#pragma unroll
    for (int g = 0; g < 4; ++g) {
        const int gr = g * H + hg * 20 + u_loc;
        bias[g] = bih1[gr] + bhh1[gr];
    }
    float cst = 0.f;
    float* hst = h2p + ((size_t)hg * 128 + bg * 8 + b_u) * 20 + u_loc;

    for (int it = 0; it <= T; ++it) {
        unsigned char* Ap = Abuf + (it & 1) * APARF;
        if (it >= stage_delta) {
            wait_flags(wait_f, wait_cnt, lane, it);
            stage_slots(sl, stage_src + (size_t)(it - stage_delta) * TSEG, Ap);
        }
        __syncthreads();

        if (it >= 1) {
            f32x4 acc = (f32x4){0.f, 0.f, 0.f, 0.f};
#pragma unroll
            for (int kt = 0; kt < 10; ++kt) {   // h1[it-1] @ Wih1^T
                const short8 ah = *(const short8*)(Ap + ((kt*2+0)*4 + kg)*256 + mm*16);
                const short8 al = *(const short8*)(Ap + ((kt*2+1)*4 + kg)*256 + mm*16);
                acc = __builtin_amdgcn_mfma_f32_16x16x32_bf16(ah, bIh[kt], acc, 0, 0, 0);
                acc = __builtin_amdgcn_mfma_f32_16x16x32_bf16(al, bIh[kt], acc, 0, 0, 0);
                acc = __builtin_amdgcn_mfma_f32_16x16x32_bf16(ah, bIl[kt], acc, 0, 0, 0);
            }
#pragma unroll
            for (int kt = 0; kt < 10; ++kt) {   // h2[it-2] @ Whh1^T
                const short8 ah = *(const short8*)(Ap + A2OFF + ((kt*2+0)*4 + kg)*256 + mm*16);
                const short8 al = *(const short8*)(Ap + A2OFF + ((kt*2+1)*4 + kg)*256 + mm*16);
                acc = __builtin_amdgcn_mfma_f32_16x16x32_bf16(ah, bHh[kt], acc, 0, 0, 0);
                acc = __builtin_amdgcn_mfma_f32_16x16x32_bf16(al, bHh[kt], acc, 0, 0, 0);
                acc = __builtin_amdgcn_mfma_f32_16x16x32_bf16(ah, bHl[kt], acc, 0, 0, 0);
            }
            if (lane < 32) {
                const int br = (lane >> 4) * 4;
#pragma unroll
                for (int r = 0; r < 4; ++r) gd[5 + ntg][br + r][mm] = acc[r];
            }
            if (upd) {
                const float* g4 = &gd[5 + ntg][b_u][u4 * 4];
                const float gi = bias[0] + g4[0], gf = bias[1] + g4[1];
                const float gz = bias[2] + g4[2], go = bias[3] + g4[3];
                const float iG = sigm(gi), fG = sigm(gf);
                const float zG = tanhfast(gz), oG = sigm(go);
                cst = fmaf(fG, cst, iG * zG);
                const float hv = oG * tanhfast(cst);
                __hip_atomic_store(hst + (size_t)(it - 1) * TSEG, hv,
                                   __ATOMIC_RELAXED, __HIP_MEMORY_SCOPE_AGENT);
            }
            asm volatile("s_waitcnt vmcnt(0)" ::: "memory");
            if (lane == 0)
                __hip_atomic_store(fpub, it + 1, __ATOMIC_RELAXED,
                                   __HIP_MEMORY_SCOPE_AGENT);
        }
    }
}

__global__ __launch_bounds__(512)
void lstm_fused(const float* __restrict__ xg0,
                const float* __restrict__ Whh0,
                const float* __restrict__ Wih1,
                const float* __restrict__ Whh1,
                const float* __restrict__ bih1,
                const float* __restrict__ bhh1,
                float* __restrict__ h1p, float* __restrict__ h2p,
                int* __restrict__ flags1g, int* __restrict__ flags2g)
{
    extern __shared__ unsigned char smem[];
    unsigned char* Abuf = smem;
    float (*gd)[8][16] = (float(*)[8][16])(smem + GDOFF);

    const int tid = threadIdx.x, wv = tid >> 6, lane = tid & 63;
    const int hg = blockIdx.x % HGC, bg = blockIdx.x / HGC;
    int* f1 = flags1g + bg * 64;    // 45 used
    int* f2 = flags2g + bg * 128;   // 75 used

    for (int i = tid; i < FLDS / 16; i += 512)
        ((uint4*)smem)[i] = make_uint4(0, 0, 0, 0);
    __syncthreads();

    if      (wv == 0) fused_g0<2>(lane, hg, bg, 0, xg0, Whh0, h1p, f1, Abuf, gd);
    else if (wv == 1) fused_g0<2>(lane, hg, bg, 2, xg0, Whh0, h1p, f1, Abuf, gd);
    else if (wv == 2) fused_g0<1>(lane, hg, bg, 4, xg0, Whh0, h1p, f1, Abuf, gd);
    else if (wv == 3) fused_g1(lane, hg, bg, 0, h1p, 1, 0, 3, f1, 45,
                               Wih1, Whh1, bih1, bhh1, h2p, f2 + hg * 5 + 0, Abuf, gd);
    else              fused_g1(lane, hg, bg, wv - 3, h2p, 2, A2OFF, wv - 4, f2, 75,
                               Wih1, Whh1, bih1, bhh1, h2p, f2 + hg * 5 + (wv - 3), Abuf, gd);
}

} // anonymous namespace

// ---------------------------------------------------------------------------
extern "C" void kernel_launch(void* const* d_in, const int* in_sizes, int n_in,
                              void* d_out, int out_size, void* d_ws, size_t ws_size,
                              hipStream_t stream)
{
    const int*   x    = (const int*)  d_in[0];
    const float* emb  = (const float*)d_in[1];
    const float* Wih0 = (const float*)d_in[2];
    const float* Whh0 = (const float*)d_in[3];
    const float* bih0 = (const float*)d_in[4];
    const float* bhh0 = (const float*)d_in[5];
    const float* Wih1 = (const float*)d_in[6];
    const float* Whh1 = (const float*)d_in[7];
    const float* bih1 = (const float*)d_in[8];
    const float* bhh1 = (const float*)d_in[9];
    const float* Wout = (const float*)d_in[10];
    const float* bout = (const float*)d_in[11];

    float* out = (float*)d_out;
    // xg0 [T][B][4H] fp32 (315 MB) aliases the output buffer (659 MB): fully
    // consumed by lstm_fused before the final GEMM overwrites d_out.
    float* xg = (float*)d_out;
    float* h1p = (float*)d_ws;                       // packed [T][15][128][20]
    float* h2p = h1p + (size_t)B * T * H;            // 78.6 MB each
    int* flags1g = (int*)(h2p + (size_t)B * T * H);  // 16 bg x 64 ints
    int* flags2g = flags1g + 16 * 64;                // 16 bg x 128 ints

    // flags must be zero each call (monotonic values; graph-captured memset)
    hipMemsetAsync(flags1g, 0, (16 * 64 + 16 * 128) * sizeof(int), stream);

    hipFuncSetAttribute(reinterpret_cast<const void*>(lstm_fused),
                        hipFuncAttributeMaxDynamicSharedMemorySize, FLDS);

    const dim3 blk(256);
    // L0 input projection (embedding gather fused)
    gemm_mfma<1, true ><<<dim3(10, 512), blk, 0, stream>>>(emb, Wih0, bih0, bhh0, x, xg, G4);
    // fused two-layer recurrence (flag-gated, packed-h)
    lstm_fused<<<dim3(NWG), dim3(512), FLDS, stream>>>(xg, Whh0, Wih1, Whh1,
                                                       bih1, bhh1, h1p, h2p,
                                                       flags1g, flags2g);
    // output projection from packed h2
    gemm_mfma<3, false><<<dim3(20, 512), blk, 0, stream>>>(h2p, Wout, bout, nullptr, nullptr, out, NVOC);
}

// Round 11
// 3671.139 us; speedup vs baseline: 1.1553x; 1.1553x over previous
//
#include <hip/hip_runtime.h>
#include <cstdint>
#include <cstddef>

namespace {

constexpr int H    = 300;
constexpr int G4   = 1200;   // 4*H
constexpr int B    = 128;
constexpr int T    = 512;
constexpr int NVOC = 2514;

typedef __attribute__((ext_vector_type(8))) short  short8;
typedef __attribute__((ext_vector_type(4))) float  f32x4;

__device__ __forceinline__ float sigm(float x)     { return 1.f / (1.f + __expf(-x)); }
__device__ __forceinline__ float tanhfast(float x) { return 1.f - 2.f / (__expf(2.f*x) + 1.f); }

__device__ __forceinline__ unsigned short bf16_rn(float f) {
    unsigned u = __float_as_uint(f);
    u += 0x7FFFu + ((u >> 16) & 1u);
    return (unsigned short)(u >> 16);
}
__device__ __forceinline__ float bf16_f(unsigned short s) {
    return __uint_as_float(((unsigned)s) << 16);
}
__device__ __forceinline__ unsigned pack2(unsigned short lo16, unsigned short hi16) {
    return (unsigned)lo16 | ((unsigned)hi16 << 16);
}

// packed h layout: idx(t, hg, b, u) = ((t*15 + hg)*128 + b)*20 + u
constexpr int TSEG = 15 * 128 * 20;   // floats per t-slice (38400)

// ---------------------------------------------------------------------------
// MFMA split-precision GEMM (unchanged from round 10). AMODE 0: row=m.
// 1: embedding gather. 2: [b,t]<->[t,b] permute. 3: packed-h A.
// ---------------------------------------------------------------------------
template<int AMODE, bool HASB2>
__global__ __launch_bounds__(256)
void gemm_mfma(const float* __restrict__ A, const float* __restrict__ W,
               const float* __restrict__ b1, const float* __restrict__ b2,
               const int* __restrict__ tok, float* __restrict__ out, int N)
{
    __shared__ __align__(16) unsigned short Ah[128][40], Al[128][40];
    __shared__ __align__(16) unsigned short Wh[128][40], Wl[128][40];

    const int tid = threadIdx.x;
    const int m0 = blockIdx.y * 128, n0 = blockIdx.x * 128;
    const int rl = tid >> 1, cb = (tid & 1) * 16;

    const int m = m0 + rl;
    const float* aptr;
    if (AMODE == 0) aptr = A + (size_t)m * H;
    else if (AMODE == 3) aptr = A + (size_t)(m & 511) * TSEG + (m >> 9) * 20;
    else {
        const int q = ((m & 127) << 9) + (m >> 7);
        aptr = A + (size_t)((AMODE == 1) ? tok[q] : q) * H;
    }
    const int nrow = n0 + rl;
    const float* wptr = W + (size_t)nrow * H;
    const bool nok = (nrow < N);

    const int wv = tid >> 6, lane = tid & 63;
    const int mw = (wv >> 1) * 64, nw = (wv & 1) * 64;
    const int kg = lane >> 4, mm = lane & 15;

    f32x4 acc[4][4];
#pragma unroll
    for (int i = 0; i < 4; ++i)
#pragma unroll
        for (int j = 0; j < 4; ++j) acc[i][j] = (f32x4){0.f, 0.f, 0.f, 0.f};

    for (int kt = 0; kt < 10; ++kt) {
        const int kbase = kt * 32;
        float4 av[4], wvv[4];
#pragma unroll
        for (int j = 0; j < 4; ++j) {
            const int col = kbase + cb + j * 4;
            const bool kv = (col <= H - 4);
            if (AMODE == 3)
                av[j] = kv ? *(const float4*)(aptr + (col / 20) * 2560 + col % 20)
                           : make_float4(0, 0, 0, 0);
            else
                av[j] = kv ? *(const float4*)(aptr + col) : make_float4(0, 0, 0, 0);
            wvv[j] = (kv && nok) ? *(const float4*)(wptr + col) : make_float4(0, 0, 0, 0);
        }
        __syncthreads();
#pragma unroll
        for (int j = 0; j < 4; ++j) {
            const float a[4] = {av[j].x,  av[j].y,  av[j].z,  av[j].w};
            const float w[4] = {wvv[j].x, wvv[j].y, wvv[j].z, wvv[j].w};
            unsigned short ah[4], al_[4], wh[4], wl[4];
#pragma unroll
            for (int e = 0; e < 4; ++e) {
                ah[e] = bf16_rn(a[e]); al_[e] = bf16_rn(a[e] - bf16_f(ah[e]));
                wh[e] = bf16_rn(w[e]); wl[e]  = bf16_rn(w[e] - bf16_f(wh[e]));
            }
            const int cc = cb + j * 4;
            *(uint2*)&Ah[rl][cc] = make_uint2(pack2(ah[0],ah[1]),  pack2(ah[2],ah[3]));
            *(uint2*)&Al[rl][cc] = make_uint2(pack2(al_[0],al_[1]),pack2(al_[2],al_[3]));
            *(uint2*)&Wh[rl][cc] = make_uint2(pack2(wh[0],wh[1]),  pack2(wh[2],wh[3]));
            *(uint2*)&Wl[rl][cc] = make_uint2(pack2(wl[0],wl[1]),  pack2(wl[2],wl[3]));
        }
        __syncthreads();

        short8 fah[4], fal[4], fbh[4], fbl[4];
#pragma unroll
        for (int f = 0; f < 4; ++f) {
            fah[f] = *(const short8*)&Ah[mw + f*16 + mm][kg*8];
            fal[f] = *(const short8*)&Al[mw + f*16 + mm][kg*8];
            fbh[f] = *(const short8*)&Wh[nw + f*16 + mm][kg*8];
            fbl[f] = *(const short8*)&Wl[nw + f*16 + mm][kg*8];
        }
#pragma unroll
        for (int mf = 0; mf < 4; ++mf)
#pragma unroll
            for (int nf = 0; nf < 4; ++nf) {
                acc[mf][nf] = __builtin_amdgcn_mfma_f32_16x16x32_bf16(fah[mf], fbh[nf], acc[mf][nf], 0, 0, 0);
                acc[mf][nf] = __builtin_amdgcn_mfma_f32_16x16x32_bf16(fal[mf], fbh[nf], acc[mf][nf], 0, 0, 0);
                acc[mf][nf] = __builtin_amdgcn_mfma_f32_16x16x32_bf16(fah[mf], fbl[nf], acc[mf][nf], 0, 0, 0);
            }
    }

    float bias[4];
#pragma unroll
    for (int nf = 0; nf < 4; ++nf) {
        const int n = n0 + nw + nf*16 + mm;
        float v = 0.f;
        if (n < N) { v = b1[n]; if (HASB2) v += b2[n]; }
        bias[nf] = v;
    }
    const int qr = lane >> 4;
#pragma unroll
    for (int mf = 0; mf < 4; ++mf) {
        const int row = m0 + mw + mf*16 + qr*4;
        float* orow = out + (size_t)row * N;
#pragma unroll
        for (int nf = 0; nf < 4; ++nf) {
            const int n = n0 + nw + nf*16 + mm;
            if (n < N) {
#pragma unroll
                for (int r = 0; r < 4; ++r)
                    orow[(size_t)r * N + n] = acc[mf][nf][r] + bias[nf];
            }
        }
    }
}

// ---------------------------------------------------------------------------
// Sentinel fill (data-as-flag protocol; h in (-1,1) is never NaN)
// ---------------------------------------------------------------------------
constexpr unsigned SENT = 0x7FB00F0Fu;

__global__ __launch_bounds__(256)
void sentinel_fill(uint4* __restrict__ p, size_t n4)
{
    const uint4 s = make_uint4(SENT, SENT, SENT, SENT);
    size_t i = (size_t)blockIdx.x * blockDim.x + threadIdx.x;
    const size_t stride = (size_t)gridDim.x * blockDim.x;
    for (; i < n4; i += stride) p[i] = s;
}

// ---------------------------------------------------------------------------
// v11 fused recurrence — COALESCED data-as-flag on the packed t-major layout.
// Poll = fetch (one RT, v9-proven) but slots are now CONTIGUOUS: the t-slice
// holds a bg's data as 15 chunks of 640 contiguous bytes, so adjacent lanes
// poll adjacent 8B words -> ~160 line-transactions per scan per CU instead of
// v9's 2560 scattered. No flags, no vmcnt drain, no fences.
// Staging ownership: waves 0-3 poll h1 hg-chunks {0-3,4-7,8-11,12-14};
// waves 4-7 poll h2 likewise. <=5 slots/lane. One __syncthreads per iter.
// ---------------------------------------------------------------------------
constexpr int HGC = 15;
constexpr int BGC = 16;
constexpr int NWG = HGC * BGC;   // 240
constexpr int A2OFF = 20480;
constexpr int APARF = 40960;
constexpr int GDOFF = 2 * APARF;
constexpr int FLDS  = GDOFF + 10 * 8 * 16 * 4;   // 87040 B

struct StageCtx {
    size_t   src64[5];   // b64 index within a t-slice
    int      aoffHi[5];  // A-fragment hi-plane byte offset
    unsigned pend0;
};

__device__ __forceinline__ void stage_init(StageCtx& S, int lane, int bg,
                                           int base_hg, int nchunks, int region)
{
    const int words = nchunks * 80;   // 80 b64 words per (hg,bg) chunk
    S.pend0 = 0;
#pragma unroll
    for (int j = 0; j < 5; ++j) {
        const int s = lane + 64 * j;
        const bool ok = (s < words);
        const int chunk = ok ? s / 80 : 0, rem = ok ? s % 80 : 0;
        const int hg = base_hg + chunk;
        S.src64[j] = (size_t)(hg * 128 + bg * 8) * 10 + rem;
        const int u2 = rem * 2, b_loc = u2 / 20, u = u2 % 20;
        const int k = hg * 20 + u;
        const int kt = k >> 5, kq = (k >> 3) & 3, pos = k & 7;
        S.aoffHi[j] = region + ((kt * 2) * 4 + kq) * 256 + b_loc * 16 + pos * 2;
        if (ok) S.pend0 |= 1u << j;
    }
}

__device__ __forceinline__ void stage_poll(const StageCtx& S,
                                           const float* __restrict__ slice,
                                           unsigned char* Ap)
{
    const unsigned long long* s64 = (const unsigned long long*)slice;
    unsigned long long val[5];
    unsigned pend = S.pend0;
    while (__any(pend != 0)) {
        unsigned long long w[5];
#pragma unroll
        for (int j = 0; j < 5; ++j)
            if (pend & (1u << j))
                w[j] = __hip_atomic_load(s64 + S.src64[j], __ATOMIC_RELAXED,
                                         __HIP_MEMORY_SCOPE_AGENT);
#pragma unroll
        for (int j = 0; j < 5; ++j)
            if (pend & (1u << j)) {
                const unsigned long long x = w[j];
                if ((unsigned)x != SENT && (unsigned)(x >> 32) != SENT) {
                    val[j] = x; pend &= ~(1u << j);
                }
            }
    }
#pragma unroll
    for (int j = 0; j < 5; ++j)
        if (S.pend0 & (1u << j)) {
            const float v0 = __uint_as_float((unsigned)val[j]);
            const float v1 = __uint_as_float((unsigned)(val[j] >> 32));
            const unsigned short h0 = bf16_rn(v0), h1_ = bf16_rn(v1);
            *(unsigned*)(Ap + S.aoffHi[j]) = pack2(h0, h1_);
            *(unsigned*)(Ap + S.aoffHi[j] + 1024) =
                pack2(bf16_rn(v0 - bf16_f(h0)), bf16_rn(v1 - bf16_f(h1_)));
        }
}

// ---- L0 waves (wv 0-2): stage h1 chunks, MFMA, L0 update + h1 publish ------
template<int NTN>
__device__ void fused_g0(int lane, int hg, int bg, int NT0, int base_hg,
                         int nchunks,
                         const float* __restrict__ xg0,
                         const float* __restrict__ Whh0,
                         float* __restrict__ h1p,
                         unsigned char* __restrict__ Abuf, float (*gd)[8][16])
{
    const int kg = lane >> 4, mm = lane & 15;

    short8 bh[10][NTN], bl[10][NTN];
#pragma unroll
    for (int kt = 0; kt < 10; ++kt)
#pragma unroll
        for (int j = 0; j < NTN; ++j) {
            const int c = (NT0 + j) * 16 + mm;
            const int grow = (c & 3) * H + hg * 20 + (c >> 2);
            short8 hi, lo;
#pragma unroll
            for (int e = 0; e < 8; ++e) {
                const int k = kt * 32 + kg * 8 + e;
                const float v = (k < H) ? Whh0[(size_t)grow * H + k] : 0.f;
                const unsigned short h16 = bf16_rn(v);
                hi[e] = (short)h16;
                lo[e] = (short)bf16_rn(v - bf16_f(h16));
            }
            bh[kt][j] = hi; bl[kt][j] = lo;
        }

    StageCtx S; stage_init(S, lane, bg, base_hg, nchunks, 0);

    const int sh = (NTN == 2) ? 3 : 2;
    const bool upd = lane < (NTN << 5);
    const int b_u = lane >> sh, u4 = lane & ((1 << sh) - 1);
    const int u_loc = NT0 * 4 + u4;
    const int ntl = NT0 + (u4 >> 2), u_rel = u4 & 3;
    float cst = 0.f;

    const float* xb0 = xg0 + (size_t)(bg * 8 + b_u) * G4 + hg * 20 + u_loc;
    float* hst = h1p + ((size_t)hg * 128 + bg * 8 + b_u) * 20 + u_loc;

    for (int it = 0; it <= T; ++it) {
        float xv0 = 0.f, xv1 = 0.f, xv2 = 0.f, xv3 = 0.f;
        if (upd && it < T) {
            const float* xb = xb0 + (size_t)it * B * G4;
            xv0 = xb[0]; xv1 = xb[H]; xv2 = xb[2 * H]; xv3 = xb[3 * H];
        }
        unsigned char* Ap = Abuf + (it & 1) * APARF;
        if (it >= 1) stage_poll(S, h1p + (size_t)(it - 1) * TSEG, Ap);
        __syncthreads();

        if (it < T) {
            f32x4 a0 = (f32x4){0.f,0.f,0.f,0.f}, a1 = (f32x4){0.f,0.f,0.f,0.f};
#pragma unroll
            for (int kt = 0; kt < 10; ++kt) {
                const short8 ah = *(const short8*)(Ap + ((kt*2+0)*4 + kg)*256 + mm*16);
                const short8 al = *(const short8*)(Ap + ((kt*2+1)*4 + kg)*256 + mm*16);
                a0 = __builtin_amdgcn_mfma_f32_16x16x32_bf16(ah, bh[kt][0], a0, 0, 0, 0);
                a0 = __builtin_amdgcn_mfma_f32_16x16x32_bf16(al, bh[kt][0], a0, 0, 0, 0);
                a0 = __builtin_amdgcn_mfma_f32_16x16x32_bf16(ah, bl[kt][0], a0, 0, 0, 0);
                if (NTN > 1) {
                    a1 = __builtin_amdgcn_mfma_f32_16x16x32_bf16(ah, bh[kt][1], a1, 0, 0, 0);
                    a1 = __builtin_amdgcn_mfma_f32_16x16x32_bf16(al, bh[kt][1], a1, 0, 0, 0);
                    a1 = __builtin_amdgcn_mfma_f32_16x16x32_bf16(ah, bl[kt][1], a1, 0, 0, 0);
                }
            }
            if (lane < 32) {
                const int br = (lane >> 4) * 4;
#pragma unroll
                for (int r = 0; r < 4; ++r) gd[NT0][br + r][mm] = a0[r];
                if (NTN > 1)
#pragma unroll
                    for (int r = 0; r < 4; ++r) gd[NT0 + 1][br + r][mm] = a1[r];
            }
            if (upd) {
                const float* g4 = &gd[ntl][b_u][u_rel * 4];
                const float gi = xv0 + g4[0], gf = xv1 + g4[1];
                const float gz = xv2 + g4[2], go = xv3 + g4[3];
                const float iG = sigm(gi), fG = sigm(gf);
                const float zG = tanhfast(gz), oG = sigm(go);
                cst = fmaf(fG, cst, iG * zG);
                const float hv = oG * tanhfast(cst);
                __hip_atomic_store(hst + (size_t)it * TSEG, hv,
                                   __ATOMIC_RELAXED, __HIP_MEMORY_SCOPE_AGENT);
            }
        }
    }
}

// ---- L1 waves (wv 3-7): stage (h1|h2) chunks, dual MFMA, L1 update ---------
__device__ void fused_g1(int lane, int hg, int bg, int ntg,
                         const float* __restrict__ stage_src, int stage_delta,
                         int stage_region, int base_hg, int nchunks,
                         const float* __restrict__ Wih1,
                         const float* __restrict__ Whh1,
                         const float* __restrict__ bih1,
                         const float* __restrict__ bhh1,
                         float* __restrict__ h2p,
                         unsigned char* __restrict__ Abuf, float (*gd)[8][16])
{
    const int kg = lane >> 4, mm = lane & 15;
    const int c = ntg * 16 + mm;
    const int grow = (c & 3) * H + hg * 20 + (c >> 2);

    short8 bIh[10], bIl[10], bHh[10], bHl[10];
#pragma unroll
    for (int kt = 0; kt < 10; ++kt) {
        short8 ih, il, hh, hl;
#pragma unroll
        for (int e = 0; e < 8; ++e) {
            const int k = kt * 32 + kg * 8 + e;
            const float vi = (k < H) ? Wih1[(size_t)grow * H + k] : 0.f;
            const float vh = (k < H) ? Whh1[(size_t)grow * H + k] : 0.f;
            const unsigned short i16 = bf16_rn(vi), h16 = bf16_rn(vh);
            ih[e] = (short)i16; il[e] = (short)bf16_rn(vi - bf16_f(i16));
            hh[e] = (short)h16; hl[e] = (short)bf16_rn(vh - bf16_f(h16));
        }
        bIh[kt] = ih; bIl[kt] = il; bHh[kt] = hh; bHl[kt] = hl;
    }

    StageCtx S; stage_init(S, lane, bg, base_hg, nchunks, stage_region);

    const bool upd = lane < 32;
    const int b_u = lane >> 2, u4 = lane & 3;
    const int u_loc = ntg * 4 + u4;
    float bias[4];
#pragma unroll
    for (int g = 0; g < 4; ++g) {
        const int gr = g * H + hg * 20 + u_loc;
        bias[g] = bih1[gr] + bhh1[gr];
    }
    float cst = 0.f;
    float* hst = h2p + ((size_t)hg * 128 + bg * 8 + b_u) * 20 + u_loc;

    for (int it = 0; it <= T; ++it) {
        unsigned char* Ap = Abuf + (it & 1) * APARF;
        if (it >= stage_delta)
            stage_poll(S, stage_src + (size_t)(it - stage_delta) * TSEG, Ap);
        __syncthreads();

        if (it >= 1) {
            f32x4 acc = (f32x4){0.f, 0.f, 0.f, 0.f};
#pragma unroll
            for (int kt = 0; kt < 10; ++kt) {   // h1[it-1] @ Wih1^T
                const short8 ah = *(const short8*)(Ap + ((kt*2+0)*4 + kg)*256 + mm*16);
                const short8 al = *(const short8*)(Ap + ((kt*2+1)*4 + kg)*256 + mm*16);
                acc = __builtin_amdgcn_mfma_f32_16x16x32_bf16(ah, bIh[kt], acc, 0, 0, 0);
                acc = __builtin_amdgcn_mfma_f32_16x16x32_bf16(al, bIh[kt], acc, 0, 0, 0);
                acc = __builtin_amdgcn_mfma_f32_16x16x32_bf16(ah, bIl[kt], acc, 0, 0, 0);
            }
#pragma unroll
            for (int kt = 0; kt < 10; ++kt) {   // h2[it-2] @ Whh1^T
                const short8 ah = *(const short8*)(Ap + A2OFF + ((kt*2+0)*4 + kg)*256 + mm*16);
                const short8 al = *(const short8*)(Ap + A2OFF + ((kt*2+1)*4 + kg)*256 + mm*16);
                acc = __builtin_amdgcn_mfma_f32_16x16x32_bf16(ah, bHh[kt], acc, 0, 0, 0);
                acc = __builtin_amdgcn_mfma_f32_16x16x32_bf16(al, bHh[kt], acc, 0, 0, 0);
                acc = __builtin_amdgcn_mfma_f32_16x16x32_bf16(ah, bHl[kt], acc, 0, 0, 0);
            }
            if (lane < 32) {
                const int br = (lane >> 4) * 4;
#pragma unroll
                for (int r = 0; r < 4; ++r) gd[5 + ntg][br + r][mm] = acc[r];
            }
            if (upd) {
                const float* g4 = &gd[5 + ntg][b_u][u4 * 4];
                const float gi = bias[0] + g4[0], gf = bias[1] + g4[1];
                const float gz = bias[2] + g4[2], go = bias[3] + g4[3];
                const float iG = sigm(gi), fG = sigm(gf);
                const float zG = tanhfast(gz), oG = sigm(go);
                cst = fmaf(fG, cst, iG * zG);
                const float hv = oG * tanhfast(cst);
                __hip_atomic_store(hst + (size_t)(it - 1) * TSEG, hv,
                                   __ATOMIC_RELAXED, __HIP_MEMORY_SCOPE_AGENT);
            }
        }
    }
}

__global__ __launch_bounds__(512)
void lstm_fused(const float* __restrict__ xg0,
                const float* __restrict__ Whh0,
                const float* __restrict__ Wih1,
                const float* __restrict__ Whh1,
                const float* __restrict__ bih1,
                const float* __restrict__ bhh1,
                float* __restrict__ h1p, float* __restrict__ h2p)
{
    extern __shared__ unsigned char smem[];
    unsigned char* Abuf = smem;
    float (*gd)[8][16] = (float(*)[8][16])(smem + GDOFF);

    const int tid = threadIdx.x, wv = tid >> 6, lane = tid & 63;
    const int hg = blockIdx.x % HGC, bg = blockIdx.x / HGC;

    for (int i = tid; i < FLDS / 16; i += 512)
        ((uint4*)smem)[i] = make_uint4(0, 0, 0, 0);
    __syncthreads();

    if      (wv == 0) fused_g0<2>(lane, hg, bg, 0,  0, 4, xg0, Whh0, h1p, Abuf, gd);
    else if (wv == 1) fused_g0<2>(lane, hg, bg, 2,  4, 4, xg0, Whh0, h1p, Abuf, gd);
    else if (wv == 2) fused_g0<1>(lane, hg, bg, 4,  8, 4, xg0, Whh0, h1p, Abuf, gd);
    else if (wv == 3) fused_g1(lane, hg, bg, 0, h1p, 1, 0,     12, 3,
                               Wih1, Whh1, bih1, bhh1, h2p, Abuf, gd);
    else              fused_g1(lane, hg, bg, wv - 3, h2p, 2, A2OFF,
                               (wv - 4) * 4, (wv == 7) ? 3 : 4,
                               Wih1, Whh1, bih1, bhh1, h2p, Abuf, gd);
}

} // anonymous namespace

// ---------------------------------------------------------------------------
extern "C" void kernel_launch(void* const* d_in, const int* in_sizes, int n_in,
                              void* d_out, int out_size, void* d_ws, size_t ws_size,
                              hipStream_t stream)
{
    const int*   x    = (const int*)  d_in[0];
    const float* emb  = (const float*)d_in[1];
    const float* Wih0 = (const float*)d_in[2];
    const float* Whh0 = (const float*)d_in[3];
    const float* bih0 = (const float*)d_in[4];
    const float* bhh0 = (const float*)d_in[5];
    const float* Wih1 = (const float*)d_in[6];
    const float* Whh1 = (const float*)d_in[7];
    const float* bih1 = (const float*)d_in[8];
    const float* bhh1 = (const float*)d_in[9];
    const float* Wout = (const float*)d_in[10];
    const float* bout = (const float*)d_in[11];

    float* out = (float*)d_out;
    // xg0 [T][B][4H] fp32 (315 MB) aliases the output buffer (659 MB): fully
    // consumed by lstm_fused before the final GEMM overwrites d_out.
    float* xg = (float*)d_out;
    float* h1p = (float*)d_ws;                       // packed [T][15][128][20]
    float* h2p = h1p + (size_t)B * T * H;            // 78.6 MB each

    // sentinel-fill both packed h buffers (data-as-flag protocol)
    const size_t nh = 2 * (size_t)B * T * H;
    sentinel_fill<<<dim3(2048), dim3(256), 0, stream>>>((uint4*)h1p, nh / 4);

    hipFuncSetAttribute(reinterpret_cast<const void*>(lstm_fused),
                        hipFuncAttributeMaxDynamicSharedMemorySize, FLDS);

    const dim3 blk(256);
    // L0 input projection (embedding gather fused)
    gemm_mfma<1, true ><<<dim3(10, 512), blk, 0, stream>>>(emb, Wih0, bih0, bhh0, x, xg, G4);
    // fused two-layer recurrence (coalesced data-as-flag, packed-h)
    lstm_fused<<<dim3(NWG), dim3(512), FLDS, stream>>>(xg, Whh0, Wih1, Whh1,
                                                       bih1, bhh1, h1p, h2p);
    // output projection from packed h2
    gemm_mfma<3, false><<<dim3(20, 512), blk, 0, stream>>>(h2p, Wout, bout, nullptr, nullptr, out, NVOC);
}